// Round 8
// baseline (71.496 us; speedup 1.0000x reference)
//
#include <hip/hip_runtime.h>
#include <math.h>

#define D_MODEL 2048
#define NUM_EXP 64
#define TOKB    64
#define STEPS   32            // K-steps of 64 floats
#define NBUF    4

typedef _Float16 f16x8 __attribute__((ext_vector_type(8)));
typedef float    f32x4 __attribute__((ext_vector_type(4)));

__device__ __forceinline__ void gload16(const void* g, void* l) {
    __builtin_amdgcn_global_load_lds(
        (const __attribute__((address_space(1))) unsigned int*)g,
        (__attribute__((address_space(3))) unsigned int*)l, 16, 0, 0);
}

// ---------------------------------------------------------------------------
// k0: W[64][2048] fp32 -> fragment-linear f16 hi/lo (W = wh + wl*2^-12,
// wl scaled by 4096). Frag (kc, mf): lane l holds
// A[m = mf*16 + (l&15)][k = kc*32 + (l>>4)*8 + j], flat at whf[(kc*4+mf)*64+l].
// ---------------------------------------------------------------------------
__global__ __launch_bounds__(256)
void k0_convw(const float* __restrict__ W, f16x8* __restrict__ whf,
              f16x8* __restrict__ wlf) {
    const int t    = blockIdx.x * 256 + threadIdx.x;
    const int lane = t & 63;
    const int mf   = (t >> 6) & 3;
    const int kc   = t >> 8;
    const int m    = mf * 16 + (lane & 15);
    const int k0   = kc * 32 + ((lane >> 4) << 3);
    const float* src = W + (size_t)m * D_MODEL + k0;
    f16x8 h, l;
#pragma unroll
    for (int j = 0; j < 8; ++j) {
        float v = src[j];
        _Float16 hh = (_Float16)v;
        h[j] = hh;
        l[j] = (_Float16)((v - (float)hh) * 4096.f);
    }
    whf[t] = h;
    wlf[t] = l;
}

// ---------------------------------------------------------------------------
// k1: DMA-staged fused router. Block = 4 waves = 64 tokens x 64 experts.
// Wave w owns tokens w*16..w*16+15, ALL experts (4 mf frags), full K.
// Per step (BK=64): 8 global_load_lds per wave (4x x-fp32, 2x W-hi, 2x W-lo),
// prefetch depth 2 over 4 buffers, steady-state s_waitcnt vmcnt(16) + ONE raw
// s_barrier per step (stage(s+2) writes buf (s+2)&3; concurrent readers are
// only compute(s-1) on buf (s-1)&3 — distinct mod 4 at distance 3).
// x LDS is linear [64][64] fp32; the GLOBAL source is pre-swizzled with the
// involution col4 ^= (row&7) so frag ds_read_b128s spread banks (m173/T2).
// cvt fp32->f16 hi/lo once per element (exact split, as R4-R7: absmax 0).
// Epilogue: logits -> ep tile -> per-wave softmax + top-2 (lower index wins)
// + per-block expert partials. Deterministic fixed-order sums throughout.
// ---------------------------------------------------------------------------
__global__ __launch_bounds__(256)
void k1_fused(const float* __restrict__ x, const f16x8* __restrict__ whf,
              const f16x8* __restrict__ wlf, float* __restrict__ out,
              float* __restrict__ p_part, float* __restrict__ f_part, int N) {
    const int tid  = threadIdx.x;
    const int lane = tid & 63;
    const int w    = tid >> 6;            // wave 0..3
    const int tok0 = blockIdx.x * TOKB;

    __shared__ float xs[NBUF][TOKB][64];  // 64 KB, linear (DMA dest)
    __shared__ f16x8 whs[NBUF][512];      // 32 KB
    __shared__ f16x8 wls[NBUF][512];      // 32 KB
    __shared__ float ep[TOKB][NUM_EXP];   // 16 KB
    __shared__ float p_red[4][64], f_red[4][64];

    // --- per-lane staging sources -----------------------------------------
    // x instr q: LDS slot row=(w*4+q)*4+(lane>>4), col4=lane&15 holds global
    // col4 (lane&15)^(row&7)  (involution: reader XORs the same).
    const float* xsrc[4];
#pragma unroll
    for (int q = 0; q < 4; ++q) {
        const int row = (w * 4 + q) * 4 + (lane >> 4);
        const int c   = (lane & 15) ^ (row & 7);
        xsrc[q] = x + (size_t)(tok0 + row) * D_MODEL + c * 4;
    }
    const f16x8* wsrc0 = whf + (w * 2 + 0) * 64 + lane;
    const f16x8* wsrc1 = whf + (w * 2 + 1) * 64 + lane;
    const f16x8* lsrc0 = wlf + (w * 2 + 0) * 64 + lane;
    const f16x8* lsrc1 = wlf + (w * 2 + 1) * 64 + lane;

    auto stage = [&](int s) {
        const int b = s & (NBUF - 1);
#pragma unroll
        for (int q = 0; q < 4; ++q)
            gload16(xsrc[q] + (size_t)s * 64, &xs[b][(w * 4 + q) * 4][0]);
        gload16(wsrc0 + (size_t)s * 512, &whs[b][(w * 2 + 0) * 64]);
        gload16(wsrc1 + (size_t)s * 512, &whs[b][(w * 2 + 1) * 64]);
        gload16(lsrc0 + (size_t)s * 512, &wls[b][(w * 2 + 0) * 64]);
        gload16(lsrc1 + (size_t)s * 512, &wls[b][(w * 2 + 1) * 64]);
    };

    f32x4 acc1[4], acc2[4];
#pragma unroll
    for (int mf = 0; mf < 4; ++mf) {
        acc1[mf] = f32x4{0.f, 0.f, 0.f, 0.f};
        acc2[mf] = f32x4{0.f, 0.f, 0.f, 0.f};
    }

    const int ft = lane & 15;
    const int fs = lane >> 4;
    const int e  = ft & 7;                // swizzle key (row&7 of this lane's row)
    const int r  = w * 16 + ft;           // this lane's token row

    stage(0);
    stage(1);
    for (int s = 0; s < STEPS; ++s) {
        if (s + 2 < STEPS) stage(s + 2);
        asm volatile("s_waitcnt vmcnt(16)" ::: "memory");
        __builtin_amdgcn_s_barrier();
        asm volatile("" ::: "memory");

        const int b = s & (NBUF - 1);
        const char* xb = (const char*)&xs[b][r][0];
#pragma unroll
        for (int kcl = 0; kcl < 2; ++kcl) {
            const float4 u0 = *(const float4*)(xb + (((kcl * 8 + fs * 2 + 0) ^ e) << 4));
            const float4 u1 = *(const float4*)(xb + (((kcl * 8 + fs * 2 + 1) ^ e) << 4));
            const float v[8] = {u0.x, u0.y, u0.z, u0.w, u1.x, u1.y, u1.z, u1.w};
            f16x8 xh, xl;
#pragma unroll
            for (int j = 0; j < 8; ++j) {
                _Float16 h = (_Float16)v[j];
                xh[j] = h;
                xl[j] = (_Float16)((v[j] - (float)h) * 4096.f);
            }
#pragma unroll
            for (int mf = 0; mf < 4; ++mf) {
                const f16x8 wh = whs[b][kcl * 256 + mf * 64 + lane];
                const f16x8 wl = wls[b][kcl * 256 + mf * 64 + lane];
                acc1[mf] = __builtin_amdgcn_mfma_f32_16x16x32_f16(wh, xh, acc1[mf], 0, 0, 0);
                acc2[mf] = __builtin_amdgcn_mfma_f32_16x16x32_f16(wh, xl, acc2[mf], 0, 0, 0);
                acc2[mf] = __builtin_amdgcn_mfma_f32_16x16x32_f16(wl, xh, acc2[mf], 0, 0, 0);
            }
        }
    }

    // --- epilogue: logits tile (C: col=lane&15=token, row=(lane>>4)*4+p) ---
#pragma unroll
    for (int mf = 0; mf < 4; ++mf) {
        f32x4 o = acc1[mf] + acc2[mf] * (1.f / 4096.f);
        *(f32x4*)&ep[r][mf * 16 + fs * 4] = o;
    }
    __syncthreads();

    // --- softmax + top-2 for this wave's 16 tokens (lane == expert) --------
    float pacc = 0.f, facc = 0.f;
#pragma unroll
    for (int i = 0; i < 16; ++i) {
        const int tl = w * 16 + i;
        float logit = ep[tl][lane];

        float m = logit;
        for (int off = 32; off; off >>= 1) m = fmaxf(m, __shfl_xor(m, off));
        float p = __expf(logit - m);
        float S = p;
        for (int off = 32; off; off >>= 1) S += __shfl_xor(S, off);
        float prob = p / S;

        float bv = logit; int bi = lane;
        for (int off = 32; off; off >>= 1) {
            float ov = __shfl_xor(bv, off);
            int   oi = __shfl_xor(bi, off);
            if (ov > bv || (ov == bv && oi < bi)) { bv = ov; bi = oi; }
        }
        float cv = (lane == bi) ? -INFINITY : logit;
        int   ci = lane;
        for (int off = 32; off; off >>= 1) {
            float ov = __shfl_xor(cv, off);
            int   oi = __shfl_xor(ci, off);
            if (ov > cv || (ov == cv && oi < ci)) { cv = ov; ci = oi; }
        }

        if (lane == 0) {
            const int gt = tok0 + tl;
            float w0 = 1.f / (1.f + __expf(cv - bv));
            out[(size_t)gt * 2]     = w0;
            out[(size_t)gt * 2 + 1] = 1.f - w0;
            out[(size_t)2 * N + gt * 2]     = (float)bi;
            out[(size_t)2 * N + gt * 2 + 1] = (float)ci;
        }

        pacc += prob;
        facc += (lane == bi ? 1.f : 0.f) + (lane == ci ? 1.f : 0.f);
    }

    p_red[w][lane] = pacc;
    f_red[w][lane] = facc;
    __syncthreads();
    if (w == 0) {
        float sp = p_red[0][lane] + p_red[1][lane] + p_red[2][lane] + p_red[3][lane];
        float sf = f_red[0][lane] + f_red[1][lane] + f_red[2][lane] + f_red[3][lane];
        p_part[(size_t)blockIdx.x * NUM_EXP + lane] = sp;
        f_part[(size_t)blockIdx.x * NUM_EXP + lane] = sf;
    }
}

// ---------------------------------------------------------------------------
// k3: deterministic aux-loss reduction over per-block partials.
// aux = E * sum_i (f_sum_i / N) * (p_sum_i / N)
// ---------------------------------------------------------------------------
__global__ __launch_bounds__(1024)
void k3_aux(const float* __restrict__ p_part, const float* __restrict__ f_part,
            float* __restrict__ out, int N, int B2) {
    const int lane = threadIdx.x & 63;
    const int wid  = threadIdx.x >> 6;
    float sp = 0.f, sf = 0.f;
    for (int b = wid; b < B2; b += 16) {
        sp += p_part[(size_t)b * NUM_EXP + lane];
        sf += f_part[(size_t)b * NUM_EXP + lane];
    }
    __shared__ float lsp[16][64];
    __shared__ float lsf[16][64];
    lsp[wid][lane] = sp;
    lsf[wid][lane] = sf;
    __syncthreads();
    if (wid == 0) {
        float tsp = 0.f, tsf = 0.f;
#pragma unroll
        for (int w2 = 0; w2 < 16; ++w2) { tsp += lsp[w2][lane]; tsf += lsf[w2][lane]; }
        float v = tsp * tsf;
        for (int off = 32; off; off >>= 1) v += __shfl_xor(v, off);
        if (lane == 0)
            out[(size_t)4 * N] = (float)NUM_EXP * v / ((float)N * (float)N);
    }
}

extern "C" void kernel_launch(void* const* d_in, const int* in_sizes, int n_in,
                              void* d_out, int out_size, void* d_ws, size_t ws_size,
                              hipStream_t stream) {
    const float* x = (const float*)d_in[0];
    const float* W = (const float*)d_in[1];
    float* out = (float*)d_out;

    const int N  = in_sizes[0] / D_MODEL;   // 16384
    const int B1 = N / TOKB;                // 256 blocks

    // ws: [whf 256KB][wlf 256KB][p_part 64KB][f_part 64KB]
    f16x8* whf = (f16x8*)d_ws;
    f16x8* wlf = whf + 16384;
    float* p_part = (float*)(wlf + 16384);
    float* f_part = p_part + (size_t)B1 * NUM_EXP;

    k0_convw<<<64, 256, 0, stream>>>(W, whf, wlf);
    k1_fused<<<B1, 256, 0, stream>>>(x, whf, wlf, out, p_part, f_part, N);
    k3_aux<<<1, 1024, 0, stream>>>(p_part, f_part, out, N, B1);
}